// Round 1
// baseline (3713.507 us; speedup 1.0000x reference)
//
#include <hip/hip_runtime.h>

#define NN 100000
#define IC 128
#define HD 128
#define OC 64
#define NE 1000000

// ---------------- degree (in-degree at dst) ----------------
__global__ __launch_bounds__(256) void k_deg(const int* __restrict__ dst,
                                             float* __restrict__ deg) {
    int e = blockIdx.x * 256 + threadIdx.x;
    if (e < NE) atomicAdd(deg + dst[e], 1.0f);
}

// ---------------- scatter-add: agg[dst] += feat[src] ----------------
// 32 threads per edge, one float4 (4 channels) per thread.
__global__ __launch_bounds__(256) void k_scatter(const float* __restrict__ feat,
                                                 const int* __restrict__ src,
                                                 const int* __restrict__ dst,
                                                 float* __restrict__ agg) {
    long long tid = (long long)blockIdx.x * 256 + threadIdx.x;
    int e = (int)(tid >> 5);
    if (e >= NE) return;
    int c4 = ((int)tid & 31) << 2;
    int s = src[e], d = dst[e];
    float4 v = *(const float4*)(feat + (size_t)s * IC + c4);
    float* p = agg + (size_t)d * IC + c4;
    atomicAdd(p + 0, v.x);
    atomicAdd(p + 1, v.y);
    atomicAdd(p + 2, v.z);
    atomicAdd(p + 3, v.w);
}

// ---------------- fused SAGE GEMM ----------------
// out = (agg/max(deg,1)) @ Wl + X @ Wr + b   [+ relu / split epilogue]
// MODE 0: layer1 -> relu -> out0 (stride 128)
// MODE 1: layer2 -> c<64 to out0=mu (stride 64), c>=64 to out1=logstd
// 256 threads: (t&31) = channel group (4 ch), (t>>5) = node slot, 8 nodes/thread.
template <int MODE>
__global__ __launch_bounds__(256) void k_gemm(
    const float* __restrict__ Agg, const float* __restrict__ X,
    const float* __restrict__ deg,
    const float* __restrict__ WlA, const float* __restrict__ WrA, const float* __restrict__ bA,
    const float* __restrict__ WlB, const float* __restrict__ WrB, const float* __restrict__ bB,
    float* __restrict__ out0, float* __restrict__ out1) {
    const int cg = threadIdx.x & 31;
    const int slot = threadIdx.x >> 5;
    const int c4 = cg << 2;
    const int nbase = blockIdx.x * 64 + slot * 8;

    const float* wlp;
    const float* wrp;
    const float* bp;
    int ldw;
    if (MODE == 0) {
        wlp = WlA + c4; wrp = WrA + c4; bp = bA + c4; ldw = HD;
    } else {
        ldw = OC;
        if (c4 < OC) { wlp = WlA + c4;        wrp = WrA + c4;        bp = bA + c4; }
        else         { wlp = WlB + (c4 - OC); wrp = WrB + (c4 - OC); bp = bB + (c4 - OC); }
    }
    const float4 bias = {bp[0], bp[1], bp[2], bp[3]};

    float acc[8][4];
#pragma unroll
    for (int j = 0; j < 8; ++j)
#pragma unroll
        for (int q = 0; q < 4; ++q) acc[j][q] = 0.f;

    float inv[8];
    const float* ar[8];
    const float* xr[8];
#pragma unroll
    for (int j = 0; j < 8; ++j) {
        int i = nbase + j;
        int ic = (i < NN) ? i : 0;
        inv[j] = (i < NN) ? (1.0f / fmaxf(deg[ic], 1.0f)) : 0.f;
        ar[j] = Agg + (size_t)ic * IC;
        xr[j] = X + (size_t)ic * IC;
    }

    for (int k = 0; k < IC; k += 4) {
        float4 a[8], xv[8];
#pragma unroll
        for (int j = 0; j < 8; ++j) {
            a[j] = *(const float4*)(ar[j] + k);
            xv[j] = *(const float4*)(xr[j] + k);
            a[j].x *= inv[j]; a[j].y *= inv[j]; a[j].z *= inv[j]; a[j].w *= inv[j];
        }
#define SAGE_STEP(KK, COMP)                                              \
    {                                                                    \
        const float4 wl = *(const float4*)(wlp + (k + KK) * ldw);        \
        const float4 wr = *(const float4*)(wrp + (k + KK) * ldw);        \
        _Pragma("unroll") for (int j = 0; j < 8; ++j) {                  \
            const float av = a[j].COMP;                                  \
            const float xx = xv[j].COMP;                                 \
            acc[j][0] = fmaf(av, wl.x, fmaf(xx, wr.x, acc[j][0]));       \
            acc[j][1] = fmaf(av, wl.y, fmaf(xx, wr.y, acc[j][1]));       \
            acc[j][2] = fmaf(av, wl.z, fmaf(xx, wr.z, acc[j][2]));       \
            acc[j][3] = fmaf(av, wl.w, fmaf(xx, wr.w, acc[j][3]));       \
        }                                                                \
    }
        SAGE_STEP(0, x)
        SAGE_STEP(1, y)
        SAGE_STEP(2, z)
        SAGE_STEP(3, w)
#undef SAGE_STEP
    }

#pragma unroll
    for (int j = 0; j < 8; ++j) {
        int i = nbase + j;
        if (i >= NN) continue;
        float4 r;
        r.x = acc[j][0] + bias.x;
        r.y = acc[j][1] + bias.y;
        r.z = acc[j][2] + bias.z;
        r.w = acc[j][3] + bias.w;
        if (MODE == 0) {
            r.x = fmaxf(r.x, 0.f); r.y = fmaxf(r.y, 0.f);
            r.z = fmaxf(r.z, 0.f); r.w = fmaxf(r.w, 0.f);
            *(float4*)(out0 + (size_t)i * HD + c4) = r;
        } else {
            if (c4 < OC) *(float4*)(out0 + (size_t)i * OC + c4) = r;
            else         *(float4*)(out1 + (size_t)i * OC + (c4 - OC)) = r;
        }
    }
}

extern "C" void kernel_launch(void* const* d_in, const int* in_sizes, int n_in,
                              void* d_out, int out_size, void* d_ws, size_t ws_size,
                              hipStream_t stream) {
    const float* x   = (const float*)d_in[0];
    const int*   ei  = (const int*)d_in[1];
    const float* W1l = (const float*)d_in[2];
    const float* W1r = (const float*)d_in[3];
    const float* b1  = (const float*)d_in[4];
    const float* Wml = (const float*)d_in[5];
    const float* Wmr = (const float*)d_in[6];
    const float* bm  = (const float*)d_in[7];
    const float* Wsl = (const float*)d_in[8];
    const float* Wsr = (const float*)d_in[9];
    const float* bs  = (const float*)d_in[10];

    const int* src = ei;        // edge_index[0]
    const int* dst = ei + NE;   // edge_index[1]

    float* deg = (float*)d_ws;                 // NN floats (400000 B, 16B-aligned)
    float* agg = deg + NN;                     // NN*128 floats
    float* h   = agg + (size_t)NN * IC;        // NN*128 floats

    float* out_mu = (float*)d_out;
    float* out_ls = out_mu + (size_t)NN * OC;

    const int scatter_grid = (int)(((long long)NE * 32 + 255) / 256);
    const int gemm_grid = (NN + 63) / 64;

    // zero deg + agg in one pass
    hipMemsetAsync(d_ws, 0, ((size_t)NN + (size_t)NN * IC) * sizeof(float), stream);

    // layer 1
    k_deg<<<(NE + 255) / 256, 256, 0, stream>>>(dst, deg);
    k_scatter<<<scatter_grid, 256, 0, stream>>>(x, src, dst, agg);
    k_gemm<0><<<gemm_grid, 256, 0, stream>>>(agg, x, deg, W1l, W1r, b1,
                                             nullptr, nullptr, nullptr, h, nullptr);

    // layer 2 (shared aggregation for mu and logstd)
    hipMemsetAsync(agg, 0, (size_t)NN * IC * sizeof(float), stream);
    k_scatter<<<scatter_grid, 256, 0, stream>>>(h, src, dst, agg);
    k_gemm<1><<<gemm_grid, 256, 0, stream>>>(agg, h, deg, Wml, Wmr, bm,
                                             Wsl, Wsr, bs, out_mu, out_ls);
}

// Round 2
// 1011.926 us; speedup vs baseline: 3.6697x; 3.6697x over previous
//
#include <hip/hip_runtime.h>

#define NN 100000
#define IC 128
#define HD 128
#define OC 64
#define NE 1000000
#define SCAN_T 1024

// ---------------- CSR build step 1: histogram of dst ----------------
__global__ __launch_bounds__(256) void k_hist(const int* __restrict__ dst,
                                              int* __restrict__ cnt) {
    int e = blockIdx.x * 256 + threadIdx.x;
    if (e < NE) atomicAdd(cnt + dst[e], 1);
}

// ---------------- CSR build step 2: exclusive scan (single block) ----------------
__global__ __launch_bounds__(SCAN_T) void k_scan(const int* __restrict__ cnt,
                                                 int* __restrict__ row_ptr,
                                                 int* __restrict__ fill_off) {
    __shared__ int psum[SCAN_T];
    const int CH = (NN + SCAN_T - 1) / SCAN_T;  // 98
    const int t = threadIdx.x;
    const int beg = t * CH;
    const int end = (beg + CH < NN) ? beg + CH : NN;
    int s = 0;
    for (int i = beg; i < end; ++i) s += cnt[i];
    psum[t] = s;
    __syncthreads();
    for (int off = 1; off < SCAN_T; off <<= 1) {
        int u = (t >= off) ? psum[t - off] : 0;
        __syncthreads();
        psum[t] += u;
        __syncthreads();
    }
    int run = psum[t] - s;  // exclusive prefix of this thread's chunk
    for (int i = beg; i < end; ++i) {
        row_ptr[i] = run;
        fill_off[i] = run;
        run += cnt[i];
    }
    if (t == 0) row_ptr[NN] = NE;
}

// ---------------- CSR build step 3: fill src lists ----------------
__global__ __launch_bounds__(256) void k_fill(const int* __restrict__ src,
                                              const int* __restrict__ dst,
                                              int* __restrict__ fill_off,
                                              int* __restrict__ csr) {
    int e = blockIdx.x * 256 + threadIdx.x;
    if (e >= NE) return;
    int pos = atomicAdd(fill_off + dst[e], 1);
    csr[pos] = src[e];
}

// ---------------- gather aggregation: agg[i] = mean_{j in N(i)} feat[j] ----------------
// one wave (64 lanes) per node, float2 per lane -> 512B coalesced row reads.
__global__ __launch_bounds__(256) void k_agg(const float* __restrict__ feat,
                                             const int* __restrict__ row_ptr,
                                             const int* __restrict__ csr,
                                             float* __restrict__ agg) {
    int node = blockIdx.x * 4 + (threadIdx.x >> 6);
    if (node >= NN) return;
    const int lane = threadIdx.x & 63;
    const int beg = row_ptr[node];
    const int end = row_ptr[node + 1];
    float sx = 0.f, sy = 0.f;
    for (int j = beg; j < end; ++j) {
        int s = csr[j];  // wave-uniform -> scalar load
        float2 v = *(const float2*)(feat + (size_t)s * IC + lane * 2);
        sx += v.x;
        sy += v.y;
    }
    float inv = 1.0f / fmaxf((float)(end - beg), 1.0f);
    float2 r = {sx * inv, sy * inv};
    *(float2*)(agg + (size_t)node * IC + lane * 2) = r;
}

// ---------------- fused SAGE GEMM ----------------
// out = Agg @ Wl + X @ Wr + b   (Agg pre-normalized)
// MODE 0: layer1 -> relu -> out0 (stride 128)
// MODE 1: layer2 -> c<64 to out0=mu (stride 64), c>=64 to out1=logstd
template <int MODE>
__global__ __launch_bounds__(256) void k_gemm(
    const float* __restrict__ Agg, const float* __restrict__ X,
    const float* __restrict__ WlA, const float* __restrict__ WrA, const float* __restrict__ bA,
    const float* __restrict__ WlB, const float* __restrict__ WrB, const float* __restrict__ bB,
    float* __restrict__ out0, float* __restrict__ out1) {
    const int cg = threadIdx.x & 31;
    const int slot = threadIdx.x >> 5;
    const int c4 = cg << 2;
    const int nbase = blockIdx.x * 64 + slot * 8;

    const float* wlp;
    const float* wrp;
    const float* bp;
    int ldw;
    if (MODE == 0) {
        wlp = WlA + c4; wrp = WrA + c4; bp = bA + c4; ldw = HD;
    } else {
        ldw = OC;
        if (c4 < OC) { wlp = WlA + c4;        wrp = WrA + c4;        bp = bA + c4; }
        else         { wlp = WlB + (c4 - OC); wrp = WrB + (c4 - OC); bp = bB + (c4 - OC); }
    }
    const float4 bias = {bp[0], bp[1], bp[2], bp[3]};

    float acc[8][4];
#pragma unroll
    for (int j = 0; j < 8; ++j)
#pragma unroll
        for (int q = 0; q < 4; ++q) acc[j][q] = 0.f;

    const float* ar[8];
    const float* xr[8];
#pragma unroll
    for (int j = 0; j < 8; ++j) {
        int i = nbase + j;
        int ic = (i < NN) ? i : 0;
        ar[j] = Agg + (size_t)ic * IC;
        xr[j] = X + (size_t)ic * IC;
    }

    for (int k = 0; k < IC; k += 4) {
        float4 a[8], xv[8];
#pragma unroll
        for (int j = 0; j < 8; ++j) {
            a[j] = *(const float4*)(ar[j] + k);
            xv[j] = *(const float4*)(xr[j] + k);
        }
#define SAGE_STEP(KK, COMP)                                              \
    {                                                                    \
        const float4 wl = *(const float4*)(wlp + (k + KK) * ldw);        \
        const float4 wr = *(const float4*)(wrp + (k + KK) * ldw);        \
        _Pragma("unroll") for (int j = 0; j < 8; ++j) {                  \
            const float av = a[j].COMP;                                  \
            const float xx = xv[j].COMP;                                 \
            acc[j][0] = fmaf(av, wl.x, fmaf(xx, wr.x, acc[j][0]));       \
            acc[j][1] = fmaf(av, wl.y, fmaf(xx, wr.y, acc[j][1]));       \
            acc[j][2] = fmaf(av, wl.z, fmaf(xx, wr.z, acc[j][2]));       \
            acc[j][3] = fmaf(av, wl.w, fmaf(xx, wr.w, acc[j][3]));       \
        }                                                                \
    }
        SAGE_STEP(0, x)
        SAGE_STEP(1, y)
        SAGE_STEP(2, z)
        SAGE_STEP(3, w)
#undef SAGE_STEP
    }

#pragma unroll
    for (int j = 0; j < 8; ++j) {
        int i = nbase + j;
        if (i >= NN) continue;
        float4 r;
        r.x = acc[j][0] + bias.x;
        r.y = acc[j][1] + bias.y;
        r.z = acc[j][2] + bias.z;
        r.w = acc[j][3] + bias.w;
        if (MODE == 0) {
            r.x = fmaxf(r.x, 0.f); r.y = fmaxf(r.y, 0.f);
            r.z = fmaxf(r.z, 0.f); r.w = fmaxf(r.w, 0.f);
            *(float4*)(out0 + (size_t)i * HD + c4) = r;
        } else {
            if (c4 < OC) *(float4*)(out0 + (size_t)i * OC + c4) = r;
            else         *(float4*)(out1 + (size_t)i * OC + (c4 - OC)) = r;
        }
    }
}

extern "C" void kernel_launch(void* const* d_in, const int* in_sizes, int n_in,
                              void* d_out, int out_size, void* d_ws, size_t ws_size,
                              hipStream_t stream) {
    const float* x   = (const float*)d_in[0];
    const int*   ei  = (const int*)d_in[1];
    const float* W1l = (const float*)d_in[2];
    const float* W1r = (const float*)d_in[3];
    const float* b1  = (const float*)d_in[4];
    const float* Wml = (const float*)d_in[5];
    const float* Wmr = (const float*)d_in[6];
    const float* bm  = (const float*)d_in[7];
    const float* Wsl = (const float*)d_in[8];
    const float* Wsr = (const float*)d_in[9];
    const float* bs  = (const float*)d_in[10];

    const int* src = ei;        // edge_index[0]
    const int* dst = ei + NE;   // edge_index[1]

    // workspace layout
    int* cnt      = (int*)d_ws;                    // NN
    int* row_ptr  = cnt + NN;                      // NN+1
    int* fill_off = row_ptr + NN + 1;              // NN
    int* csr      = fill_off + NN;                 // NE
    float* agg    = (float*)(csr + NE + 1);        // NN*128 (keep 8B align; base is fine)
    float* h      = agg + (size_t)NN * IC;         // NN*128

    float* out_mu = (float*)d_out;
    float* out_ls = out_mu + (size_t)NN * OC;

    const int gemm_grid = (NN + 63) / 64;
    const int agg_grid = (NN + 3) / 4;

    // ---- CSR build (shared by both layers) ----
    hipMemsetAsync(cnt, 0, (size_t)NN * sizeof(int), stream);
    k_hist<<<(NE + 255) / 256, 256, 0, stream>>>(dst, cnt);
    k_scan<<<1, SCAN_T, 0, stream>>>(cnt, row_ptr, fill_off);
    k_fill<<<(NE + 255) / 256, 256, 0, stream>>>(src, dst, fill_off, csr);

    // ---- layer 1 ----
    k_agg<<<agg_grid, 256, 0, stream>>>(x, row_ptr, csr, agg);
    k_gemm<0><<<gemm_grid, 256, 0, stream>>>(agg, x, W1l, W1r, b1,
                                             nullptr, nullptr, nullptr, h, nullptr);

    // ---- layer 2 (shared aggregation feeds mu and logstd) ----
    k_agg<<<agg_grid, 256, 0, stream>>>(h, row_ptr, csr, agg);
    k_gemm<1><<<gemm_grid, 256, 0, stream>>>(agg, h, Wml, Wmr, bm,
                                             Wsl, Wsr, bs, out_mu, out_ls);
}

// Round 3
// 562.262 us; speedup vs baseline: 6.6046x; 1.7997x over previous
//
#include <hip/hip_runtime.h>

#define NN 100000
#define IC 128
#define OC 64
#define NE 1000000
#define SCAN_T 1024

typedef __attribute__((ext_vector_type(8))) short short8;
typedef __attribute__((ext_vector_type(4))) float f32x4;

static __device__ __forceinline__ float b2f(unsigned short u) {
    unsigned v = ((unsigned)u) << 16;
    float f;
    __builtin_memcpy(&f, &v, 4);
    return f;
}
static __device__ __forceinline__ unsigned short f2b(float f) {
    unsigned u;
    __builtin_memcpy(&u, &f, 4);
    u += 0x7fff + ((u >> 16) & 1);
    return (unsigned short)(u >> 16);
}

// ---------------- CSR build ----------------
__global__ __launch_bounds__(256) void k_hist(const int* __restrict__ dst,
                                              int* __restrict__ cnt) {
    int e = blockIdx.x * 256 + threadIdx.x;
    if (e < NE) atomicAdd(cnt + dst[e], 1);
}

__global__ __launch_bounds__(SCAN_T) void k_scan(const int* __restrict__ cnt,
                                                 int* __restrict__ row_ptr,
                                                 int* __restrict__ fill_off) {
    __shared__ int psum[SCAN_T];
    const int CH = (NN + SCAN_T - 1) / SCAN_T;
    const int t = threadIdx.x;
    const int beg = t * CH;
    const int end = (beg + CH < NN) ? beg + CH : NN;
    int s = 0;
    for (int i = beg; i < end; ++i) s += cnt[i];
    psum[t] = s;
    __syncthreads();
    for (int off = 1; off < SCAN_T; off <<= 1) {
        int u = (t >= off) ? psum[t - off] : 0;
        __syncthreads();
        psum[t] += u;
        __syncthreads();
    }
    int run = psum[t] - s;
    for (int i = beg; i < end; ++i) {
        row_ptr[i] = run;
        fill_off[i] = run;
        run += cnt[i];
    }
    if (t == 0) row_ptr[NN] = NE;
}

__global__ __launch_bounds__(256) void k_fill(const int* __restrict__ src,
                                              const int* __restrict__ dst,
                                              int* __restrict__ fill_off,
                                              int* __restrict__ csr) {
    int e = blockIdx.x * 256 + threadIdx.x;
    if (e >= NE) return;
    int pos = atomicAdd(fill_off + dst[e], 1);
    csr[pos] = src[e];
}

// ---------------- x fp32 -> bf16 ----------------
__global__ __launch_bounds__(256) void k_cvt(const float* __restrict__ x,
                                             unsigned short* __restrict__ xb) {
    int t = blockIdx.x * 256 + threadIdx.x;
    if (t >= NN * IC / 8) return;
    const float4* p = (const float4*)x + (size_t)t * 2;
    float4 f0 = p[0], f1 = p[1];
    short8 o;
    o[0] = (short)f2b(f0.x); o[1] = (short)f2b(f0.y);
    o[2] = (short)f2b(f0.z); o[3] = (short)f2b(f0.w);
    o[4] = (short)f2b(f1.x); o[5] = (short)f2b(f1.y);
    o[6] = (short)f2b(f1.z); o[7] = (short)f2b(f1.w);
    *((short8*)xb + t) = o;
}

// ---------------- weight prep: stack [Wl;Wr] (K=256) and transpose to col-major bf16 ----------------
__global__ __launch_bounds__(256) void k_wprep(
    const float* __restrict__ W1l, const float* __restrict__ W1r,
    const float* __restrict__ Wml, const float* __restrict__ Wmr,
    const float* __restrict__ Wsl, const float* __restrict__ Wsr,
    unsigned short* __restrict__ Wt1, unsigned short* __restrict__ Wt2) {
    int t = blockIdx.x * 256 + threadIdx.x;
    if (t >= 2 * 128 * 256) return;
    int layer = t >> 15;
    int rem = t & 32767;
    int col = rem >> 8;
    int k = rem & 255;
    float v;
    if (layer == 0) {
        v = (k < 128) ? W1l[k * 128 + col] : W1r[(k - 128) * 128 + col];
        Wt1[col * 256 + k] = f2b(v);
    } else {
        if (col < OC) v = (k < 128) ? Wml[k * OC + col] : Wmr[(k - 128) * OC + col];
        else {
            int c2 = col - OC;
            v = (k < 128) ? Wsl[k * OC + c2] : Wsr[(k - 128) * OC + c2];
        }
        Wt2[col * 256 + k] = f2b(v);
    }
}

// ---------------- gather mean-aggregation (bf16 in/out, f32 accum) ----------------
// one wave per node; 4 neighbor slots x 16 lanes (8ch each, 16B loads)
__global__ __launch_bounds__(256) void k_agg(const unsigned short* __restrict__ feat,
                                             const int* __restrict__ row_ptr,
                                             const int* __restrict__ csr,
                                             unsigned short* __restrict__ agg) {
    int node = blockIdx.x * 4 + (threadIdx.x >> 6);
    if (node >= NN) return;
    const int lane = threadIdx.x & 63;
    const int slot = lane >> 4;
    const int cg = lane & 15;
    const int beg = row_ptr[node];
    const int end = row_ptr[node + 1];
    float acc[8];
#pragma unroll
    for (int q = 0; q < 8; ++q) acc[q] = 0.f;

    for (int j0 = beg; j0 < end; j0 += 4) {
        int j = j0 + slot;
        if (j < end) {
            int s = csr[j];
            short8 v = *(const short8*)(feat + (size_t)s * IC + cg * 8);
#pragma unroll
            for (int q = 0; q < 8; ++q) acc[q] += b2f((unsigned short)v[q]);
        }
    }
#pragma unroll
    for (int q = 0; q < 8; ++q) {
        acc[q] += __shfl_xor(acc[q], 16, 64);
        acc[q] += __shfl_xor(acc[q], 32, 64);
    }
    if (slot == 0) {
        float inv = 1.0f / fmaxf((float)(end - beg), 1.0f);
        short8 o;
#pragma unroll
        for (int q = 0; q < 8; ++q) o[q] = (short)f2b(acc[q] * inv);
        *(short8*)(agg + (size_t)node * IC + cg * 8) = o;
    }
}

// ---------------- MFMA SAGE GEMM: out = [Agg | X] @ Wt + b ----------------
// block = 256 threads (4 waves); wave -> 32 rows x 128 cols; K=256 in 8 steps.
// MODE 0: +bias, relu, write h bf16 (stride 128)
// MODE 1: +bias, write mu (cols 0-63) / logstd (cols 64-127) fp32 stride 64
template <int MODE>
__global__ __launch_bounds__(256) void k_gemm(
    const unsigned short* __restrict__ Agg, const unsigned short* __restrict__ Xb,
    const unsigned short* __restrict__ Wt,
    const float* __restrict__ bias0, const float* __restrict__ bias1,
    unsigned short* __restrict__ hout, float* __restrict__ out_mu,
    float* __restrict__ out_ls) {
    const int lane = threadIdx.x & 63;
    const int wid = threadIdx.x >> 6;
    const int rowb = blockIdx.x * 128 + wid * 32;
    const int r16 = lane & 15;
    const int k8 = (lane >> 4) * 8;

    f32x4 acc[2][8];
#pragma unroll
    for (int m = 0; m < 2; ++m)
#pragma unroll
        for (int nt = 0; nt < 8; ++nt) acc[m][nt] = (f32x4){0.f, 0.f, 0.f, 0.f};

    int rA[2];
#pragma unroll
    for (int m = 0; m < 2; ++m) {
        int r = rowb + m * 16 + r16;
        rA[m] = (r < NN) ? r : (NN - 1);
    }

#pragma unroll
    for (int ks = 0; ks < 8; ++ks) {
        const int kbase = ks * 32;
        const unsigned short* Ah = (kbase < 128) ? Agg : Xb;
        const int koff = (kbase & 127) + k8;
        short8 aF[2];
        aF[0] = *(const short8*)(Ah + (size_t)rA[0] * IC + koff);
        aF[1] = *(const short8*)(Ah + (size_t)rA[1] * IC + koff);
#pragma unroll
        for (int nt = 0; nt < 8; ++nt) {
            short8 bF = *(const short8*)(Wt + (nt * 16 + r16) * 256 + kbase + k8);
            acc[0][nt] = __builtin_amdgcn_mfma_f32_16x16x32_bf16(aF[0], bF, acc[0][nt], 0, 0, 0);
            acc[1][nt] = __builtin_amdgcn_mfma_f32_16x16x32_bf16(aF[1], bF, acc[1][nt], 0, 0, 0);
        }
    }

    const int rbase = (lane >> 4) * 4;
#pragma unroll
    for (int m = 0; m < 2; ++m) {
#pragma unroll
        for (int nt = 0; nt < 8; ++nt) {
            const int c = nt * 16 + r16;
            const float bv = (MODE == 0) ? bias0[c] : (c < OC ? bias0[c] : bias1[c - OC]);
#pragma unroll
            for (int r = 0; r < 4; ++r) {
                const int row = rowb + m * 16 + rbase + r;
                if (row >= NN) continue;
                float v = acc[m][nt][r] + bv;
                if (MODE == 0) {
                    v = fmaxf(v, 0.f);
                    hout[(size_t)row * IC + c] = f2b(v);
                } else {
                    if (c < OC) out_mu[(size_t)row * OC + c] = v;
                    else        out_ls[(size_t)row * OC + (c - OC)] = v;
                }
            }
        }
    }
}

extern "C" void kernel_launch(void* const* d_in, const int* in_sizes, int n_in,
                              void* d_out, int out_size, void* d_ws, size_t ws_size,
                              hipStream_t stream) {
    const float* x   = (const float*)d_in[0];
    const int*   ei  = (const int*)d_in[1];
    const float* W1l = (const float*)d_in[2];
    const float* W1r = (const float*)d_in[3];
    const float* b1  = (const float*)d_in[4];
    const float* Wml = (const float*)d_in[5];
    const float* Wmr = (const float*)d_in[6];
    const float* bm  = (const float*)d_in[7];
    const float* Wsl = (const float*)d_in[8];
    const float* Wsr = (const float*)d_in[9];
    const float* bs  = (const float*)d_in[10];

    const int* src = ei;
    const int* dst = ei + NE;

    // workspace layout (bytes; all 16B-aligned)
    char* w = (char*)d_ws;
    unsigned short* xb   = (unsigned short*)(w);                       // 25,600,000 B
    unsigned short* hb   = (unsigned short*)(w + 25600000);            // 25,600,000 B
    unsigned short* aggb = (unsigned short*)(w + 51200000);            // 25,600,000 B
    unsigned short* Wt1  = (unsigned short*)(w + 76800000);            // 65,536 B
    unsigned short* Wt2  = (unsigned short*)(w + 76865536);            // 65,536 B
    int* cnt      = (int*)(w + 76931072);                              // 400,000 B
    int* row_ptr  = (int*)(w + 77331072);                              // 400,004 B
    int* fill_off = (int*)(w + 77731076);                              // 400,000 B
    int* csr      = (int*)(w + 78131076);                              // 4,000,000 B

    float* out_mu = (float*)d_out;
    float* out_ls = out_mu + (size_t)NN * OC;

    const int gemm_grid = (NN + 127) / 128;
    const int agg_grid = (NN + 3) / 4;

    // CSR build (shared by both layers)
    hipMemsetAsync(cnt, 0, (size_t)NN * sizeof(int), stream);
    k_hist<<<(NE + 255) / 256, 256, 0, stream>>>(dst, cnt);
    k_scan<<<1, SCAN_T, 0, stream>>>(cnt, row_ptr, fill_off);
    k_fill<<<(NE + 255) / 256, 256, 0, stream>>>(src, dst, fill_off, csr);

    // conversions / weight prep
    k_cvt<<<(NN * IC / 8 + 255) / 256, 256, 0, stream>>>(x, xb);
    k_wprep<<<(2 * 128 * 256 + 255) / 256, 256, 0, stream>>>(W1l, W1r, Wml, Wmr, Wsl, Wsr, Wt1, Wt2);

    // layer 1
    k_agg<<<agg_grid, 256, 0, stream>>>(xb, row_ptr, csr, aggb);
    k_gemm<0><<<gemm_grid, 256, 0, stream>>>(aggb, xb, Wt1, b1, nullptr,
                                             hb, nullptr, nullptr);

    // layer 2 (shared aggregation feeds mu and logstd)
    k_agg<<<agg_grid, 256, 0, stream>>>(hb, row_ptr, csr, aggb);
    k_gemm<1><<<gemm_grid, 256, 0, stream>>>(aggb, hb, Wt2, bm, bs,
                                             nullptr, out_mu, out_ls);
}

// Round 4
// 348.443 us; speedup vs baseline: 10.6574x; 1.6136x over previous
//
#include <hip/hip_runtime.h>

#define NN 100000
#define IC 128
#define OC 64
#define NE 1000000

#define SCAN_BLK 256
#define SCAN_ITEMS 4
#define SCAN_TILE 1024
#define NB ((NN + SCAN_TILE - 1) / SCAN_TILE)  // 98

typedef __attribute__((ext_vector_type(8))) short short8;
typedef __attribute__((ext_vector_type(4))) float f32x4;

static __device__ __forceinline__ float b2f(unsigned short u) {
    unsigned v = ((unsigned)u) << 16;
    float f;
    __builtin_memcpy(&f, &v, 4);
    return f;
}
static __device__ __forceinline__ unsigned short f2b(float f) {
    unsigned u;
    __builtin_memcpy(&u, &f, 4);
    u += 0x7fff + ((u >> 16) & 1);
    return (unsigned short)(u >> 16);
}

// ---------------- CSR build step 1: histogram of dst ----------------
__global__ __launch_bounds__(256) void k_hist(const int* __restrict__ dst,
                                              int* __restrict__ cnt) {
    int e = blockIdx.x * 256 + threadIdx.x;
    if (e < NE) atomicAdd(cnt + dst[e], 1);
}

// ---------------- CSR build step 2: hierarchical exclusive scan ----------------
__global__ __launch_bounds__(SCAN_BLK) void k_scan_a(const int* __restrict__ cnt,
                                                     int* __restrict__ bsum) {
    __shared__ int red[SCAN_BLK];
    const int b = blockIdx.x;
    const int t = threadIdx.x;
    const int base = b * SCAN_TILE + t * SCAN_ITEMS;
    int s = 0;
#pragma unroll
    for (int q = 0; q < SCAN_ITEMS; ++q) {
        int i = base + q;
        if (i < NN) s += cnt[i];
    }
    red[t] = s;
    __syncthreads();
    for (int off = SCAN_BLK / 2; off > 0; off >>= 1) {
        if (t < off) red[t] += red[t + off];
        __syncthreads();
    }
    if (t == 0) bsum[b] = red[0];
}

__global__ __launch_bounds__(128) void k_scan_b(int* __restrict__ bsum) {
    __shared__ int sh[128];
    const int t = threadIdx.x;
    int v = (t < NB) ? bsum[t] : 0;
    sh[t] = v;
    __syncthreads();
    for (int off = 1; off < 128; off <<= 1) {
        int u = (t >= off) ? sh[t - off] : 0;
        __syncthreads();
        sh[t] += u;
        __syncthreads();
    }
    if (t < NB) bsum[t] = sh[t] - v;  // exclusive
}

__global__ __launch_bounds__(SCAN_BLK) void k_scan_c(const int* __restrict__ cnt,
                                                     const int* __restrict__ bsum,
                                                     int* __restrict__ row_ptr,
                                                     int* __restrict__ fill_off) {
    __shared__ int sh[SCAN_BLK];
    const int b = blockIdx.x;
    const int t = threadIdx.x;
    const int base = b * SCAN_TILE + t * SCAN_ITEMS;
    int loc[SCAN_ITEMS];
    int s = 0;
#pragma unroll
    for (int q = 0; q < SCAN_ITEMS; ++q) {
        int i = base + q;
        loc[q] = (i < NN) ? cnt[i] : 0;
        s += loc[q];
    }
    sh[t] = s;
    __syncthreads();
    for (int off = 1; off < SCAN_BLK; off <<= 1) {
        int u = (t >= off) ? sh[t - off] : 0;
        __syncthreads();
        sh[t] += u;
        __syncthreads();
    }
    int run = bsum[b] + sh[t] - s;
#pragma unroll
    for (int q = 0; q < SCAN_ITEMS; ++q) {
        int i = base + q;
        if (i < NN) {
            row_ptr[i] = run;
            fill_off[i] = run;
            run += loc[q];
        }
    }
    if (b == 0 && t == 0) row_ptr[NN] = NE;
}

// ---------------- CSR build step 3: fill src lists ----------------
__global__ __launch_bounds__(256) void k_fill(const int* __restrict__ src,
                                              const int* __restrict__ dst,
                                              int* __restrict__ fill_off,
                                              int* __restrict__ csr) {
    int e = blockIdx.x * 256 + threadIdx.x;
    if (e >= NE) return;
    int pos = atomicAdd(fill_off + dst[e], 1);
    csr[pos] = src[e];
}

// ---------------- x fp32 -> bf16 ----------------
__global__ __launch_bounds__(256) void k_cvt(const float* __restrict__ x,
                                             unsigned short* __restrict__ xb) {
    int t = blockIdx.x * 256 + threadIdx.x;
    if (t >= NN * IC / 8) return;
    const float4* p = (const float4*)x + (size_t)t * 2;
    float4 f0 = p[0], f1 = p[1];
    short8 o;
    o[0] = (short)f2b(f0.x); o[1] = (short)f2b(f0.y);
    o[2] = (short)f2b(f0.z); o[3] = (short)f2b(f0.w);
    o[4] = (short)f2b(f1.x); o[5] = (short)f2b(f1.y);
    o[6] = (short)f2b(f1.z); o[7] = (short)f2b(f1.w);
    *((short8*)xb + t) = o;
}

// ---------------- weight prep: stack [Wl;Wr] (K=256), transpose to col-major bf16 ----------------
__global__ __launch_bounds__(256) void k_wprep(
    const float* __restrict__ W1l, const float* __restrict__ W1r,
    const float* __restrict__ Wml, const float* __restrict__ Wmr,
    const float* __restrict__ Wsl, const float* __restrict__ Wsr,
    unsigned short* __restrict__ Wt1, unsigned short* __restrict__ Wt2) {
    int t = blockIdx.x * 256 + threadIdx.x;
    if (t >= 2 * 128 * 256) return;
    int layer = t >> 15;
    int rem = t & 32767;
    int col = rem >> 8;
    int k = rem & 255;
    float v;
    if (layer == 0) {
        v = (k < 128) ? W1l[k * 128 + col] : W1r[(k - 128) * 128 + col];
        Wt1[col * 256 + k] = f2b(v);
    } else {
        if (col < OC) v = (k < 128) ? Wml[k * OC + col] : Wmr[(k - 128) * OC + col];
        else {
            int c2 = col - OC;
            v = (k < 128) ? Wsl[k * OC + c2] : Wsr[(k - 128) * OC + c2];
        }
        Wt2[col * 256 + k] = f2b(v);
    }
}

// ---------------- gather mean-aggregation (bf16 in/out, f32 accum) ----------------
__global__ __launch_bounds__(256) void k_agg(const unsigned short* __restrict__ feat,
                                             const int* __restrict__ row_ptr,
                                             const int* __restrict__ csr,
                                             unsigned short* __restrict__ agg) {
    int node = blockIdx.x * 4 + (threadIdx.x >> 6);
    if (node >= NN) return;
    const int lane = threadIdx.x & 63;
    const int slot = lane >> 4;
    const int cg = lane & 15;
    const int beg = row_ptr[node];
    const int end = row_ptr[node + 1];
    float acc[8];
#pragma unroll
    for (int q = 0; q < 8; ++q) acc[q] = 0.f;

    for (int j0 = beg; j0 < end; j0 += 4) {
        int j = j0 + slot;
        if (j < end) {
            int s = csr[j];
            short8 v = *(const short8*)(feat + (size_t)s * IC + cg * 8);
#pragma unroll
            for (int q = 0; q < 8; ++q) acc[q] += b2f((unsigned short)v[q]);
        }
    }
#pragma unroll
    for (int q = 0; q < 8; ++q) {
        acc[q] += __shfl_xor(acc[q], 16, 64);
        acc[q] += __shfl_xor(acc[q], 32, 64);
    }
    if (slot == 0) {
        float inv = 1.0f / fmaxf((float)(end - beg), 1.0f);
        short8 o;
#pragma unroll
        for (int q = 0; q < 8; ++q) o[q] = (short)f2b(acc[q] * inv);
        *(short8*)(agg + (size_t)node * IC + cg * 8) = o;
    }
}

// ---------------- MFMA SAGE GEMM: out = [Agg | X] @ Wt + b ----------------
template <int MODE>
__global__ __launch_bounds__(256) void k_gemm(
    const unsigned short* __restrict__ Agg, const unsigned short* __restrict__ Xb,
    const unsigned short* __restrict__ Wt,
    const float* __restrict__ bias0, const float* __restrict__ bias1,
    unsigned short* __restrict__ hout, float* __restrict__ out_mu,
    float* __restrict__ out_ls) {
    const int lane = threadIdx.x & 63;
    const int wid = threadIdx.x >> 6;
    const int rowb = blockIdx.x * 128 + wid * 32;
    const int r16 = lane & 15;
    const int k8 = (lane >> 4) * 8;

    f32x4 acc[2][8];
#pragma unroll
    for (int m = 0; m < 2; ++m)
#pragma unroll
        for (int nt = 0; nt < 8; ++nt) acc[m][nt] = (f32x4){0.f, 0.f, 0.f, 0.f};

    int rA[2];
#pragma unroll
    for (int m = 0; m < 2; ++m) {
        int r = rowb + m * 16 + r16;
        rA[m] = (r < NN) ? r : (NN - 1);
    }

#pragma unroll
    for (int ks = 0; ks < 8; ++ks) {
        const int kbase = ks * 32;
        const unsigned short* Ah = (kbase < 128) ? Agg : Xb;
        const int koff = (kbase & 127) + k8;
        short8 aF[2];
        aF[0] = *(const short8*)(Ah + (size_t)rA[0] * IC + koff);
        aF[1] = *(const short8*)(Ah + (size_t)rA[1] * IC + koff);
#pragma unroll
        for (int nt = 0; nt < 8; ++nt) {
            short8 bF = *(const short8*)(Wt + (nt * 16 + r16) * 256 + kbase + k8);
            acc[0][nt] = __builtin_amdgcn_mfma_f32_16x16x32_bf16(aF[0], bF, acc[0][nt], 0, 0, 0);
            acc[1][nt] = __builtin_amdgcn_mfma_f32_16x16x32_bf16(aF[1], bF, acc[1][nt], 0, 0, 0);
        }
    }

    const int rbase = (lane >> 4) * 4;
#pragma unroll
    for (int m = 0; m < 2; ++m) {
#pragma unroll
        for (int nt = 0; nt < 8; ++nt) {
            const int c = nt * 16 + r16;
            const float bv = (MODE == 0) ? bias0[c] : (c < OC ? bias0[c] : bias1[c - OC]);
#pragma unroll
            for (int r = 0; r < 4; ++r) {
                const int row = rowb + m * 16 + rbase + r;
                if (row >= NN) continue;
                float v = acc[m][nt][r] + bv;
                if (MODE == 0) {
                    v = fmaxf(v, 0.f);
                    hout[(size_t)row * IC + c] = f2b(v);
                } else {
                    if (c < OC) out_mu[(size_t)row * OC + c] = v;
                    else        out_ls[(size_t)row * OC + (c - OC)] = v;
                }
            }
        }
    }
}

extern "C" void kernel_launch(void* const* d_in, const int* in_sizes, int n_in,
                              void* d_out, int out_size, void* d_ws, size_t ws_size,
                              hipStream_t stream) {
    const float* x   = (const float*)d_in[0];
    const int*   ei  = (const int*)d_in[1];
    const float* W1l = (const float*)d_in[2];
    const float* W1r = (const float*)d_in[3];
    const float* b1  = (const float*)d_in[4];
    const float* Wml = (const float*)d_in[5];
    const float* Wmr = (const float*)d_in[6];
    const float* bm  = (const float*)d_in[7];
    const float* Wsl = (const float*)d_in[8];
    const float* Wsr = (const float*)d_in[9];
    const float* bs  = (const float*)d_in[10];

    const int* src = ei;
    const int* dst = ei + NE;

    // workspace layout (bytes; all 16B-aligned)
    char* w = (char*)d_ws;
    unsigned short* xb   = (unsigned short*)(w);                       // 25,600,000 B
    unsigned short* hb   = (unsigned short*)(w + 25600000);            // 25,600,000 B
    unsigned short* aggb = (unsigned short*)(w + 51200000);            // 25,600,000 B
    unsigned short* Wt1  = (unsigned short*)(w + 76800000);            // 65,536 B
    unsigned short* Wt2  = (unsigned short*)(w + 76865536);            // 65,536 B
    int* cnt      = (int*)(w + 76931072);                              // 400,000 B
    int* row_ptr  = (int*)(w + 77331072);                              // 400,004 B
    int* fill_off = (int*)(w + 77731076);                              // 400,000 B
    int* csr      = (int*)(w + 78131076);                              // 4,000,000 B
    int* bsum     = (int*)(w + 82131076);                              // NB*4 B

    float* out_mu = (float*)d_out;
    float* out_ls = out_mu + (size_t)NN * OC;

    const int gemm_grid = (NN + 127) / 128;
    const int agg_grid = (NN + 3) / 4;

    // CSR build (shared by both layers)
    hipMemsetAsync(cnt, 0, (size_t)NN * sizeof(int), stream);
    k_hist<<<(NE + 255) / 256, 256, 0, stream>>>(dst, cnt);
    k_scan_a<<<NB, SCAN_BLK, 0, stream>>>(cnt, bsum);
    k_scan_b<<<1, 128, 0, stream>>>(bsum);
    k_scan_c<<<NB, SCAN_BLK, 0, stream>>>(cnt, bsum, row_ptr, fill_off);
    k_fill<<<(NE + 255) / 256, 256, 0, stream>>>(src, dst, fill_off, csr);

    // conversions / weight prep
    k_cvt<<<(NN * IC / 8 + 255) / 256, 256, 0, stream>>>(x, xb);
    k_wprep<<<(2 * 128 * 256 + 255) / 256, 256, 0, stream>>>(W1l, W1r, Wml, Wmr, Wsl, Wsr, Wt1, Wt2);

    // layer 1
    k_agg<<<agg_grid, 256, 0, stream>>>(xb, row_ptr, csr, aggb);
    k_gemm<0><<<gemm_grid, 256, 0, stream>>>(aggb, xb, Wt1, b1, nullptr,
                                             hb, nullptr, nullptr);

    // layer 2 (shared aggregation feeds mu and logstd)
    k_agg<<<agg_grid, 256, 0, stream>>>(hb, row_ptr, csr, aggb);
    k_gemm<1><<<gemm_grid, 256, 0, stream>>>(aggb, hb, Wt2, bm, bs,
                                             nullptr, out_mu, out_ls);
}